// Round 5
// baseline (648.887 us; speedup 1.0000x reference)
//
#include <hip/hip_runtime.h>
#include <hip/hip_bf16.h>
#include <stdint.h>
#include <stddef.h>

#define NN 8192
#define DD 128
#define PANELS 64   // fused-fallback: one partial-sum panel per j-tile

typedef __attribute__((ext_vector_type(8))) short bf16x8;
typedef __attribute__((ext_vector_type(4))) float f32x4;

static __device__ __forceinline__ unsigned short f2bf(float x) {
  __hip_bfloat16 h = __float2bfloat16(x);
  return *(unsigned short*)&h;
}

// ---------------------------------------------------------------------------
// Kernel 1: row-normalize features (fp32) and cast to bf16. One wave per row.
// ---------------------------------------------------------------------------
__global__ __launch_bounds__(256) void normalize_kernel(
    const float* __restrict__ f, __hip_bfloat16* __restrict__ fn) {
  const int wave = threadIdx.x >> 6;
  const int lane = threadIdx.x & 63;
  const int row = blockIdx.x * 4 + wave;
  const float2 v = ((const float2*)(f + (size_t)row * DD))[lane];
  float ss = v.x * v.x + v.y * v.y;
#pragma unroll
  for (int m = 1; m < 64; m <<= 1) ss += __shfl_xor(ss, m, 64);
  const float inv = 1.0f / fmaxf(sqrtf(ss), 1e-8f);
  __hip_bfloat162 o;
  o.x = __float2bfloat16(v.x * inv);
  o.y = __float2bfloat16(v.y * inv);
  ((__hip_bfloat162*)(fn + (size_t)row * DD))[lane] = o;
}

// ---------------------------------------------------------------------------
// SPLIT PATH k1: 128x128 MFMA tile -> exp(sim/T) -> bf16 E matrix in ws.
// Warp owns 32 rows x 128 cols (acc[2][8]); fragment (mt,nt,r):
//   i = I0 + mt*16 + l16,  j = J0g + nt*16 + quad*4 + r.
// Writes land in L3 (write-back); k2 re-reads them as L3 hits.
// ---------------------------------------------------------------------------
__global__ __launch_bounds__(256, 4) void sim_exp(
    const __hip_bfloat16* __restrict__ fn,
    unsigned short* __restrict__ E) {
  const int tid = threadIdx.x;
  const int lane = tid & 63;
  const int quad = lane >> 4;
  const int l16 = lane & 15;
  const int w = tid >> 6;

  const int I0g = blockIdx.y * 128;
  const int J0g = blockIdx.x * 128;
  const int I0 = I0g + w * 32;

  f32x4 acc[2][8] = {};
#pragma unroll
  for (int kt = 0; kt < 4; ++kt) {
    const int ko = kt * 32 + quad * 8;
    bf16x8 aF[2], bF[8];
#pragma unroll
    for (int mt = 0; mt < 2; ++mt)
      aF[mt] = *(const bf16x8*)(fn + (size_t)(I0 + mt * 16 + l16) * DD + ko);
#pragma unroll
    for (int nt = 0; nt < 8; ++nt)
      bF[nt] = *(const bf16x8*)(fn + (size_t)(J0g + nt * 16 + l16) * DD + ko);
#pragma unroll
    for (int mt = 0; mt < 2; ++mt)
#pragma unroll
      for (int nt = 0; nt < 8; ++nt)
        acc[mt][nt] = __builtin_amdgcn_mfma_f32_16x16x32_bf16(
            bF[nt], aF[mt], acc[mt][nt], 0, 0, 0);  // SWAPPED operands
  }

  const float tinv = 1.0f / 0.07f;
#pragma unroll
  for (int mt = 0; mt < 2; ++mt) {
    const int i = I0 + mt * 16 + l16;
    unsigned short* Er = E + (size_t)i * NN + J0g + quad * 4;
#pragma unroll
    for (int nt = 0; nt < 8; ++nt) {
      ushort4 wv;
      wv.x = f2bf(__expf(acc[mt][nt][0] * tinv));
      wv.y = f2bf(__expf(acc[mt][nt][1] * tinv));
      wv.z = f2bf(__expf(acc[mt][nt][2] * tinv));
      wv.w = f2bf(__expf(acc[mt][nt][3] * tinv));
      *(ushort4*)(Er + nt * 16) = wv;  // 8B/lane, merged in L2 write-back
    }
  }
}

// ---------------------------------------------------------------------------
// SPLIT PATH k2: pure streaming row reduction. One 256-thread block per row.
// Thread t, iter k covers cols k*1024 + t*4 .. +4: int4 pm + int4 nm +
// ushort4 E — every wave-load is 1KB/512B contiguous. 8 independent unrolled
// iterations, ~40 VGPRs -> 8 blocks/CU, deep MLP. No atomics, no panels.
// Emits the per-row loss term s_i directly.
// ---------------------------------------------------------------------------
__global__ __launch_bounds__(256) void row_reduce(
    const unsigned short* __restrict__ E,
    const int* __restrict__ pmask, const int* __restrict__ nmask,
    float* __restrict__ sRow) {
  const int i = blockIdx.x;
  const unsigned short* Er = E + (size_t)i * NN;
  const int* pr = pmask + (size_t)i * NN;
  const int* nr = nmask + (size_t)i * NN;

  float p = 0.f, q = 0.f;
  int c = 0;
#pragma unroll
  for (int k = 0; k < 8; ++k) {
    const int jb = k * 1024 + threadIdx.x * 4;
    const int4 pm4 = *(const int4*)(pr + jb);
    const int4 nm4 = *(const int4*)(nr + jb);
    const ushort4 e4 = *(const ushort4*)(Er + jb);
#pragma unroll
    for (int r = 0; r < 4; ++r) {
      int pm = (&pm4.x)[r];
      int nm = (&nm4.x)[r];
      if (jb + r == i) { pm = 0; nm = 0; }  // zero self-contrast
      const float e =
          __uint_as_float(((unsigned int)(&e4.x)[r]) << 16);
      p = fmaf(e, (float)pm, p);
      q = fmaf(e, (float)nm, q);
      c += pm;
    }
  }
  float cf = (float)c;
#pragma unroll
  for (int m = 1; m < 64; m <<= 1) {
    p += __shfl_xor(p, m, 64);
    q += __shfl_xor(q, m, 64);
    cf += __shfl_xor(cf, m, 64);
  }
  __shared__ float sp[4], sq[4], sc[4];
  const int wv = threadIdx.x >> 6;
  if ((threadIdx.x & 63) == 0) { sp[wv] = p; sq[wv] = q; sc[wv] = cf; }
  __syncthreads();
  if (threadIdx.x == 0) {
    const float P = sp[0] + sp[1] + sp[2] + sp[3];
    const float Q = sq[0] + sq[1] + sq[2] + sq[3];
    const float C = sc[0] + sc[1] + sc[2] + sc[3];
    sRow[i] = logf(P / (P + Q)) / C;
  }
}

// SPLIT PATH k3: mean over rows -> loss
__global__ __launch_bounds__(256) void finalize_split(
    const float* __restrict__ sRow, float* __restrict__ out) {
  float s = 0.f;
  for (int k = threadIdx.x; k < NN; k += 256) s += sRow[k];
#pragma unroll
  for (int m = 1; m < 64; m <<= 1) s += __shfl_xor(s, m, 64);
  __shared__ float ws4[4];
  if ((threadIdx.x & 63) == 0) ws4[threadIdx.x >> 6] = s;
  __syncthreads();
  if (threadIdx.x == 0)
    out[0] = -(ws4[0] + ws4[1] + ws4[2] + ws4[3]) / (float)NN;
}

// ===========================================================================
// FUSED FALLBACK (round-4 kernel, passing): used only if ws can't hold E.
// ===========================================================================
template <bool DIAG, bool ATOMIC>
static __device__ __forceinline__ void accum_tile(
    const f32x4 acc[2][8],
    const int* __restrict__ pmask, const int* __restrict__ nmask,
    int I0g, int J0g, int w, int quad, int l16, int panelIdx,
    float* __restrict__ pP, float* __restrict__ nP, float* __restrict__ cP) {
  const float tinv = 1.0f / 0.07f;
#pragma unroll
  for (int mt = 0; mt < 2; ++mt) {
    const int iLoc = w * 32 + mt * 16 + l16;
    const size_t mOff = (size_t)(I0g + iLoc) * NN + J0g + quad * 4;
    float pRow = 0.f, qRow = 0.f;
    int cRow = 0;
#pragma unroll
    for (int nt = 0; nt < 8; ++nt) {
      const int4 pm4 = *(const int4*)(pmask + mOff + nt * 16);
      const int4 nm4 = *(const int4*)(nmask + mOff + nt * 16);
      const int dj = DIAG ? (iLoc - (nt * 16 + quad * 4)) : -1;
#pragma unroll
      for (int r = 0; r < 4; ++r) {
        int pm = (&pm4.x)[r];
        int nm = (&nm4.x)[r];
        if (DIAG) {
          if (r == dj) { pm = 0; nm = 0; }
        }
        const float e = __expf(acc[mt][nt][r] * tinv);
        pRow = fmaf(e, (float)pm, pRow);
        qRow = fmaf(e, (float)nm, qRow);
        cRow += pm;
      }
    }
    pRow += __shfl_xor(pRow, 16, 64);
    pRow += __shfl_xor(pRow, 32, 64);
    qRow += __shfl_xor(qRow, 16, 64);
    qRow += __shfl_xor(qRow, 32, 64);
    cRow += __shfl_xor(cRow, 16, 64);
    cRow += __shfl_xor(cRow, 32, 64);
    const int iG = I0g + iLoc;
    if (ATOMIC) {
      if (quad == 0)      atomicAdd(&pP[iG], pRow);
      else if (quad == 1) atomicAdd(&nP[iG], qRow);
      else if (quad == 2) atomicAdd(&cP[iG], (float)cRow);
    } else {
      const size_t po = (size_t)panelIdx * NN + iG;
      if (quad == 0)      pP[po] = pRow;
      else if (quad == 1) nP[po] = qRow;
      else if (quad == 2) cP[po] = (float)cRow;
    }
  }
}

template <bool ATOMIC>
__global__ __launch_bounds__(256, 4) void ssnt_fused(
    const __hip_bfloat16* __restrict__ fn,
    const int* __restrict__ pmask,
    const int* __restrict__ nmask,
    float* __restrict__ pP, float* __restrict__ nP, float* __restrict__ cP) {
  const int tid = threadIdx.x;
  const int lane = tid & 63;
  const int quad = lane >> 4;
  const int l16 = lane & 15;
  const int w = tid >> 6;

  const int I0g = blockIdx.y * 128;
  const int J0g = blockIdx.x * 128;
  const int I0 = I0g + w * 32;

  f32x4 acc[2][8] = {};
#pragma unroll
  for (int kt = 0; kt < 4; ++kt) {
    const int ko = kt * 32 + quad * 8;
    bf16x8 aF[2], bF[8];
#pragma unroll
    for (int mt = 0; mt < 2; ++mt)
      aF[mt] = *(const bf16x8*)(fn + (size_t)(I0 + mt * 16 + l16) * DD + ko);
#pragma unroll
    for (int nt = 0; nt < 8; ++nt)
      bF[nt] = *(const bf16x8*)(fn + (size_t)(J0g + nt * 16 + l16) * DD + ko);
#pragma unroll
    for (int mt = 0; mt < 2; ++mt)
#pragma unroll
      for (int nt = 0; nt < 8; ++nt)
        acc[mt][nt] = __builtin_amdgcn_mfma_f32_16x16x32_bf16(
            bF[nt], aF[mt], acc[mt][nt], 0, 0, 0);
  }

  if (I0g == J0g)
    accum_tile<true, ATOMIC>(acc, pmask, nmask, I0g, J0g, w, quad, l16,
                             blockIdx.x, pP, nP, cP);
  else
    accum_tile<false, ATOMIC>(acc, pmask, nmask, I0g, J0g, w, quad, l16,
                              blockIdx.x, pP, nP, cP);
}

__global__ __launch_bounds__(256) void finalize1(
    const float* __restrict__ pP, const float* __restrict__ nP,
    const float* __restrict__ cP, int panels, float* __restrict__ blkSum) {
  const int r = blockIdx.x * 256 + threadIdx.x;
  float p = 0.f, q = 0.f, c = 0.f;
  for (int k = 0; k < panels; ++k) {
    p += pP[(size_t)k * NN + r];
    q += nP[(size_t)k * NN + r];
    c += cP[(size_t)k * NN + r];
  }
  float s = logf(p / (p + q)) / c;
#pragma unroll
  for (int m = 1; m < 64; m <<= 1) s += __shfl_xor(s, m, 64);
  __shared__ float ws4[4];
  if ((threadIdx.x & 63) == 0) ws4[threadIdx.x >> 6] = s;
  __syncthreads();
  if (threadIdx.x == 0)
    blkSum[blockIdx.x] = ws4[0] + ws4[1] + ws4[2] + ws4[3];
}

__global__ void finalize2(const float* __restrict__ blkSum,
                          float* __restrict__ out) {
  float s = (threadIdx.x < NN / 256) ? blkSum[threadIdx.x] : 0.f;
#pragma unroll
  for (int m = 1; m < 64; m <<= 1) s += __shfl_xor(s, m, 64);
  if (threadIdx.x == 0) out[0] = -s / (float)NN;
}

extern "C" void kernel_launch(void* const* d_in, const int* in_sizes, int n_in,
                              void* d_out, int out_size, void* d_ws, size_t ws_size,
                              hipStream_t stream) {
  const float* features = (const float*)d_in[0];
  const int* pmask = (const int*)d_in[1];
  const int* nmask = (const int*)d_in[2];
  float* out = (float*)d_out;

  char* ws = (char*)d_ws;
  __hip_bfloat16* fn = (__hip_bfloat16*)ws;  // 2 MB
  char* after_fn = ws + (size_t)NN * DD * sizeof(__hip_bfloat16);

  normalize_kernel<<<NN / 4, 256, 0, stream>>>(features, fn);

  const size_t needSplit = (size_t)NN * DD * 2       // fn
                         + (size_t)NN * NN * 2       // E (bf16, 128 MB)
                         + (size_t)NN * 4 + 256;     // sRow
  const size_t needPanels =
      (size_t)NN * DD * 2 + 3ull * PANELS * NN * sizeof(float) + 256;

  if (ws_size >= needSplit) {
    // split path: GEMM->E, then pure streaming reduction at HBM roofline
    unsigned short* E = (unsigned short*)after_fn;
    float* sRow = (float*)(after_fn + (size_t)NN * NN * 2);
    sim_exp<<<dim3(NN / 128, NN / 128), 256, 0, stream>>>(fn, E);
    row_reduce<<<NN, 256, 0, stream>>>(E, pmask, nmask, sRow);
    finalize_split<<<1, 256, 0, stream>>>(sRow, out);
  } else if (ws_size >= needPanels) {
    float* pP = (float*)after_fn;
    float* nP = pP + (size_t)PANELS * NN;
    float* cP = nP + (size_t)PANELS * NN;
    float* blkSum = cP + (size_t)PANELS * NN;
    ssnt_fused<false><<<dim3(NN / 128, NN / 128), 256, 0, stream>>>(
        fn, pmask, nmask, pP, nP, cP);
    finalize1<<<NN / 256, 256, 0, stream>>>(pP, nP, cP, PANELS, blkSum);
    finalize2<<<1, 64, 0, stream>>>(blkSum, out);
  } else {
    float* pP = (float*)after_fn;
    float* nP = pP + NN;
    float* cP = nP + NN;
    float* blkSum = cP + NN;
    hipMemsetAsync(pP, 0, 3 * (size_t)NN * sizeof(float), stream);
    ssnt_fused<true><<<dim3(NN / 128, NN / 128), 256, 0, stream>>>(
        fn, pmask, nmask, pP, nP, cP);
    finalize1<<<NN / 256, 256, 0, stream>>>(pP, nP, cP, 1, blkSum);
    finalize2<<<1, 64, 0, stream>>>(blkSum, out);
  }
}

// Round 6
// 570.480 us; speedup vs baseline: 1.1374x; 1.1374x over previous
//
#include <hip/hip_runtime.h>
#include <hip/hip_bf16.h>
#include <stdint.h>
#include <stddef.h>

#define NN 8192
#define DD 128
#define PADW 136   // LDS row stride (bf16): 272 B, breaks bank conflicts
#define PANELS 8   // j-panels (grid.x); each block covers SUBT j-subtiles
#define SUBT 8     // 128-col j-subtiles per block
#define ROWS 64    // i-rows per block

typedef __attribute__((ext_vector_type(8))) short bf16x8;
typedef __attribute__((ext_vector_type(4))) float f32x4;

static __device__ __forceinline__ unsigned short f2bf(float x) {
  __hip_bfloat16 h = __float2bfloat16(x);
  return *(unsigned short*)&h;
}

// ---------------------------------------------------------------------------
// Kernel 1: row-normalize features (fp32) and cast to bf16. One wave per row.
// ---------------------------------------------------------------------------
__global__ __launch_bounds__(256) void normalize_kernel(
    const float* __restrict__ f, __hip_bfloat16* __restrict__ fn) {
  const int wave = threadIdx.x >> 6;
  const int lane = threadIdx.x & 63;
  const int row = blockIdx.x * 4 + wave;
  const float2 v = ((const float2*)(f + (size_t)row * DD))[lane];
  float ss = v.x * v.x + v.y * v.y;
#pragma unroll
  for (int m = 1; m < 64; m <<= 1) ss += __shfl_xor(ss, m, 64);
  const float inv = 1.0f / fmaxf(sqrtf(ss), 1e-8f);
  __hip_bfloat162 o;
  o.x = __float2bfloat16(v.x * inv);
  o.y = __float2bfloat16(v.y * inv);
  ((__hip_bfloat162*)(fn + (size_t)row * DD))[lane] = o;
}

// ---------------------------------------------------------------------------
// Producer wave: 32 rows x 128 cols MFMA tile -> exp(sim/T) -> bf16 into LDS.
// Fragment (mt,nt,r): i = I0w + mt*16 + l16, j = J0 + nt*16 + quad*4 + r.
// ---------------------------------------------------------------------------
static __device__ __forceinline__ void produce(
    const __hip_bfloat16* __restrict__ fn, __hip_bfloat16* __restrict__ simbuf,
    int I0w, int rowBase, int J0, int quad, int l16) {
  f32x4 acc[2][8] = {};
#pragma unroll
  for (int kt = 0; kt < 4; ++kt) {
    const int ko = kt * 32 + quad * 8;
    bf16x8 aF[2], bF[8];
#pragma unroll
    for (int mt = 0; mt < 2; ++mt)
      aF[mt] = *(const bf16x8*)(fn + (size_t)(I0w + mt * 16 + l16) * DD + ko);
#pragma unroll
    for (int nt = 0; nt < 8; ++nt)
      bF[nt] = *(const bf16x8*)(fn + (size_t)(J0 + nt * 16 + l16) * DD + ko);
#pragma unroll
    for (int mt = 0; mt < 2; ++mt)
#pragma unroll
      for (int nt = 0; nt < 8; ++nt)
        acc[mt][nt] = __builtin_amdgcn_mfma_f32_16x16x32_bf16(
            bF[nt], aF[mt], acc[mt][nt], 0, 0, 0);  // SWAPPED operands
  }
  const float tinv = 1.0f / 0.07f;
#pragma unroll
  for (int mt = 0; mt < 2; ++mt) {
    const int row = rowBase + mt * 16 + l16;
#pragma unroll
    for (int nt = 0; nt < 8; ++nt) {
      const int col = nt * 16 + quad * 4;
      ushort4 w;
      w.x = f2bf(__expf(acc[mt][nt][0] * tinv));
      w.y = f2bf(__expf(acc[mt][nt][1] * tinv));
      w.z = f2bf(__expf(acc[mt][nt][2] * tinv));
      w.w = f2bf(__expf(acc[mt][nt][3] * tinv));
      *(ushort4*)(simbuf + row * PADW + col) = w;
    }
  }
}

// ---------------------------------------------------------------------------
// Consumer: row-major masked accumulation of one 64x128 E tile from LDS.
// Thread (rGrp 0..7, cl 0..15) covers rows it*8+rGrp, cols [cl*8, cl*8+8).
// Wave-load = 256B-contiguous mask bursts; lane-local partials accP/Q/C[it].
// ---------------------------------------------------------------------------
template <bool DIAG>
static __device__ __forceinline__ void consume(
    const __hip_bfloat16* __restrict__ simbuf,
    const int* __restrict__ pmask, const int* __restrict__ nmask,
    int I0g, int J0, int rGrp, int cl,
    float* __restrict__ accP, float* __restrict__ accQ,
    int* __restrict__ accC) {
#pragma unroll
  for (int it = 0; it < 8; ++it) {
    const int row = it * 8 + rGrp;
    const size_t mOff = (size_t)(I0g + row) * NN + J0 + cl * 8;
    const int4 pa = *(const int4*)(pmask + mOff);
    const int4 pb = *(const int4*)(pmask + mOff + 4);
    const int4 na = *(const int4*)(nmask + mOff);
    const int4 nb = *(const int4*)(nmask + mOff + 4);
    const bf16x8 ev = *(const bf16x8*)(simbuf + row * PADW + cl * 8);
    int pm8[8], nm8[8];
    *(int4*)&pm8[0] = pa; *(int4*)&pm8[4] = pb;
    *(int4*)&nm8[0] = na; *(int4*)&nm8[4] = nb;
    const int dj = DIAG ? ((I0g + row) - (J0 + cl * 8)) : -1;
    float p = 0.f, q = 0.f;
    int c = 0;
#pragma unroll
    for (int r = 0; r < 8; ++r) {
      int pm = pm8[r];
      int nm = nm8[r];
      if (DIAG) {
        if (r == dj) { pm = 0; nm = 0; }  // zero self-contrast
      }
      const float e = __uint_as_float(((unsigned int)(unsigned short)ev[r]) << 16);
      p = fmaf(e, (float)pm, p);
      q = fmaf(e, (float)nm, q);
      c += pm;
    }
    accP[it] += p; accQ[it] += q; accC[it] += c;
  }
}

// ---------------------------------------------------------------------------
// Kernel 2: producer/consumer wave-specialized fused kernel.
// Waves 0-1 compute E tiles (MFMA+exp) into a double-buffered LDS tile;
// waves 2-3 stream masks from HBM and reduce, one subtile behind. The mask
// stream is never gated by the GEMM (m114: MFMA/mem waves co-schedule), so
// HBM stays saturated for the whole kernel lifetime.
// ---------------------------------------------------------------------------
__global__ __launch_bounds__(256, 4) void ssnt_pc(
    const __hip_bfloat16* __restrict__ fn,
    const int* __restrict__ pmask,
    const int* __restrict__ nmask,
    float* __restrict__ pP, float* __restrict__ nP, float* __restrict__ cP) {
  __shared__ __hip_bfloat16 sim[2][ROWS * PADW];  // 2 x 17 KB -> 4 blocks/CU

  const int tid = threadIdx.x;
  const int lane = tid & 63;
  const int quad = lane >> 4;
  const int l16 = lane & 15;
  const int wv = tid >> 6;  // 0,1: producers; 2,3: consumers

  const int I0g = blockIdx.y * ROWS;
  const int Jbase = blockIdx.x * (SUBT * 128);

  if (wv < 2) {
    // ---------------- producer path ----------------
    const int I0w = I0g + wv * 32;
    const int rowBase = wv * 32;
#pragma unroll 1
    for (int js = 0; js < SUBT; ++js) {
      produce(fn, sim[js & 1], I0w, rowBase, Jbase + js * 128, quad, l16);
      __syncthreads();
    }
  } else {
    // ---------------- consumer path ----------------
    const int tid2 = tid & 127;
    const int rGrp = tid2 >> 4;  // 0..7
    const int cl = tid2 & 15;    // 0..15
    float accP[8] = {}, accQ[8] = {};
    int accC[8] = {};
#pragma unroll 1
    for (int js = 0; js < SUBT; ++js) {
      if (js > 0) {
        const int Jp = Jbase + (js - 1) * 128;
        if (((I0g ^ Jp) & ~127) == 0)
          consume<true>(sim[(js - 1) & 1], pmask, nmask, I0g, Jp, rGrp, cl,
                        accP, accQ, accC);
        else
          consume<false>(sim[(js - 1) & 1], pmask, nmask, I0g, Jp, rGrp, cl,
                         accP, accQ, accC);
      }
      __syncthreads();
    }
    {  // epilogue: last tile (producers are done; buffers stable)
      const int Jp = Jbase + (SUBT - 1) * 128;
      if (((I0g ^ Jp) & ~127) == 0)
        consume<true>(sim[(SUBT - 1) & 1], pmask, nmask, I0g, Jp, rGrp, cl,
                      accP, accQ, accC);
      else
        consume<false>(sim[(SUBT - 1) & 1], pmask, nmask, I0g, Jp, rGrp, cl,
                       accP, accQ, accC);
    }
    // reduce across the 16 cl-lanes of each row (batched: 24 indep chains)
#pragma unroll
    for (int m = 1; m < 16; m <<= 1) {
#pragma unroll
      for (int it = 0; it < 8; ++it) {
        accP[it] += __shfl_xor(accP[it], m, 64);
        accQ[it] += __shfl_xor(accQ[it], m, 64);
        accC[it] += __shfl_xor(accC[it], m, 64);
      }
    }
#pragma unroll
    for (int it = 0; it < 8; ++it) {
      const int iG = I0g + it * 8 + rGrp;
      const size_t po = (size_t)blockIdx.x * NN + iG;
      if (cl == 0)      pP[po] = accP[it];
      else if (cl == 1) nP[po] = accQ[it];
      else if (cl == 2) cP[po] = (float)accC[it];
    }
  }
}

// ---------------------------------------------------------------------------
// Kernel 3a: reduce panels per row, per-row loss term, block sum -> blkSum[32]
// ---------------------------------------------------------------------------
__global__ __launch_bounds__(256) void finalize1(
    const float* __restrict__ pP, const float* __restrict__ nP,
    const float* __restrict__ cP, float* __restrict__ blkSum) {
  const int r = blockIdx.x * 256 + threadIdx.x;
  float p = 0.f, q = 0.f, c = 0.f;
#pragma unroll
  for (int k = 0; k < PANELS; ++k) {
    p += pP[(size_t)k * NN + r];
    q += nP[(size_t)k * NN + r];
    c += cP[(size_t)k * NN + r];
  }
  float s = logf(p / (p + q)) / c;
#pragma unroll
  for (int m = 1; m < 64; m <<= 1) s += __shfl_xor(s, m, 64);
  __shared__ float ws4[4];
  if ((threadIdx.x & 63) == 0) ws4[threadIdx.x >> 6] = s;
  __syncthreads();
  if (threadIdx.x == 0)
    blkSum[blockIdx.x] = ws4[0] + ws4[1] + ws4[2] + ws4[3];
}

// Kernel 3b: final 32-value sum -> loss
__global__ void finalize2(const float* __restrict__ blkSum,
                          float* __restrict__ out) {
  float s = (threadIdx.x < NN / 256) ? blkSum[threadIdx.x] : 0.f;
#pragma unroll
  for (int m = 1; m < 64; m <<= 1) s += __shfl_xor(s, m, 64);
  if (threadIdx.x == 0) out[0] = -s / (float)NN;
}

extern "C" void kernel_launch(void* const* d_in, const int* in_sizes, int n_in,
                              void* d_out, int out_size, void* d_ws, size_t ws_size,
                              hipStream_t stream) {
  const float* features = (const float*)d_in[0];
  const int* pmask = (const int*)d_in[1];
  const int* nmask = (const int*)d_in[2];
  float* out = (float*)d_out;

  char* ws = (char*)d_ws;
  __hip_bfloat16* fn = (__hip_bfloat16*)ws;  // 2 MB
  float* pP = (float*)(ws + (size_t)NN * DD * sizeof(__hip_bfloat16));
  float* nP = pP + (size_t)PANELS * NN;      // 3 x 256 KB panels
  float* cP = nP + (size_t)PANELS * NN;
  float* blkSum = cP + (size_t)PANELS * NN;  // 128 B

  normalize_kernel<<<NN / 4, 256, 0, stream>>>(features, fn);
  ssnt_pc<<<dim3(PANELS, NN / ROWS), 256, 0, stream>>>(fn, pmask, nmask,
                                                       pP, nP, cP);
  finalize1<<<NN / 256, 256, 0, stream>>>(pP, nP, cP, blkSum);
  finalize2<<<1, 64, 0, stream>>>(blkSum, out);
}